// Round 1
// baseline (456.977 us; speedup 1.0000x reference)
//
#include <hip/hip_runtime.h>

// GraphConvModel: 2x GraphConv(norm='both') + 2x Linear+LeakyReLU
// N=50000 nodes, E=800000 edges, feats 128 -> 128 -> 128 -> 256 -> 40 (f32)

#define SCAN_B 256

// ---------------- degree count ----------------
__global__ void k_degree(const int* __restrict__ src, const int* __restrict__ dst,
                         int* __restrict__ deg_out, int* __restrict__ deg_in, int E) {
    int i = blockIdx.x * blockDim.x + threadIdx.x;
    if (i < E) {
        atomicAdd(&deg_out[src[i]], 1);
        atomicAdd(&deg_in[dst[i]], 1);
    }
}

__global__ void k_invsqrt(const int* __restrict__ deg_out, const int* __restrict__ deg_in,
                          float* __restrict__ inv_out, float* __restrict__ inv_in, int N) {
    int i = blockIdx.x * blockDim.x + threadIdx.x;
    if (i < N) {
        inv_out[i] = rsqrtf(fmaxf((float)deg_out[i], 1.0f));
        inv_in[i]  = rsqrtf(fmaxf((float)deg_in[i], 1.0f));
    }
}

// ---------------- exclusive scan of deg_in -> row_ptr (3 kernels) ----------------
__global__ void k_scanA(const int* __restrict__ deg_in, int* __restrict__ incl,
                        int* __restrict__ bsum, int N) {
    __shared__ int s[SCAN_B];
    int t = threadIdx.x, i = blockIdx.x * SCAN_B + t;
    int v = (i < N) ? deg_in[i] : 0;
    s[t] = v; __syncthreads();
    for (int o = 1; o < SCAN_B; o <<= 1) {
        int x = (t >= o) ? s[t - o] : 0;
        __syncthreads();
        s[t] += x;
        __syncthreads();
    }
    if (i < N) incl[i] = s[t];
    if (t == SCAN_B - 1) bsum[blockIdx.x] = s[t];
}

__global__ void k_scanB(int* __restrict__ bsum, int NB) {
    __shared__ int s[SCAN_B];
    int t = threadIdx.x;
    int v = (t < NB) ? bsum[t] : 0;
    s[t] = v; __syncthreads();
    for (int o = 1; o < SCAN_B; o <<= 1) {
        int x = (t >= o) ? s[t - o] : 0;
        __syncthreads();
        s[t] += x;
        __syncthreads();
    }
    if (t < NB) bsum[t] = s[t] - v;  // exclusive
}

__global__ void k_scanC(const int* __restrict__ deg_in, int* __restrict__ row_ptr,
                        const int* __restrict__ bsum, int N, int E) {
    int t = threadIdx.x, i = blockIdx.x * SCAN_B + t;
    if (i < N) row_ptr[i] = row_ptr[i] - deg_in[i] + bsum[blockIdx.x];
    if (i == 0) row_ptr[N] = E;
}

// ---------------- CSR scatter ----------------
__global__ void k_scatter(const int* __restrict__ src, const int* __restrict__ dst,
                          const int* __restrict__ row_ptr, int* __restrict__ fill,
                          int* __restrict__ edge_src, int E) {
    int i = blockIdx.x * blockDim.x + threadIdx.x;
    if (i < E) {
        int d = dst[i];
        int pos = row_ptr[d] + atomicAdd(&fill[d], 1);
        edge_src[pos] = src[i];
    }
}

// ---------------- SpMM gather: Y[i,:] = inv_in[i] * sum_e inv_out[s_e] * X[s_e,:] ----------------
__global__ void k_gather(const float* __restrict__ X, const int* __restrict__ edge_src,
                         const int* __restrict__ row_ptr, const float* __restrict__ inv_out,
                         const float* __restrict__ inv_in, float* __restrict__ Y, int N) {
    int lane = threadIdx.x & 31;
    int row = blockIdx.x * 8 + (threadIdx.x >> 5);
    if (row >= N) return;
    int rs = row_ptr[row], re = row_ptr[row + 1];
    float4 acc = {0.f, 0.f, 0.f, 0.f};
    for (int e = rs; e < re; ++e) {
        int s = edge_src[e];
        float sc = inv_out[s];
        float4 xv = *reinterpret_cast<const float4*>(&X[(size_t)s * 128 + lane * 4]);
        acc.x += xv.x * sc; acc.y += xv.y * sc; acc.z += xv.z * sc; acc.w += xv.w * sc;
    }
    float si = inv_in[row];
    float4 o = {acc.x * si, acc.y * si, acc.z * si, acc.w * si};
    *reinterpret_cast<float4*>(&Y[(size_t)row * 128 + lane * 4]) = o;
}

// ---------------- tiled f32 GEMM + bias + activation ----------------
// C[M,N] = act(A[M,K] @ W[K,N] + bias), ACT: 0=relu, 1=leaky(0.01)
template<int K, int N, int BN, int ACT>
__global__ __launch_bounds__(256) void k_gemm_act(const float* __restrict__ A,
                                                  const float* __restrict__ W,
                                                  const float* __restrict__ bias,
                                                  float* __restrict__ C, int M) {
    constexpr int BM = 64, BK = 32;
    constexpr int TN = BN / 32;
    __shared__ float As[BM][BK];
    __shared__ float Ws[BK][BN];
    int t = threadIdx.x;
    int tx = t & 31, ty = t >> 5;
    int m0 = blockIdx.x * BM;
    int cb = blockIdx.y * BN;

    float acc[8][TN];
    #pragma unroll
    for (int i = 0; i < 8; ++i)
        #pragma unroll
        for (int j = 0; j < TN; ++j) acc[i][j] = 0.f;

    for (int kk = 0; kk < K; kk += BK) {
        // stage A tile: 64x32 = 512 float4, 2 per thread
        #pragma unroll
        for (int i = 0; i < 2; ++i) {
            int g = t + i * 256;
            int row = g >> 3;
            int kc = (g & 7) * 4;
            float4 v = {0.f, 0.f, 0.f, 0.f};
            int gr = m0 + row;
            if (gr < M) v = *reinterpret_cast<const float4*>(&A[(size_t)gr * K + kk + kc]);
            *reinterpret_cast<float4*>(&As[row][kc]) = v;
        }
        // stage W tile: BK x BN, BN/32 float4 per thread
        #pragma unroll
        for (int i = 0; i < BN / 32; ++i) {
            int g = t + i * 256;
            int row = g / (BN / 4);
            int c = (g % (BN / 4)) * 4;
            float4 v = {0.f, 0.f, 0.f, 0.f};
            int gc = cb + c;
            if (gc < N) v = *reinterpret_cast<const float4*>(&W[(size_t)(kk + row) * N + gc]);
            *reinterpret_cast<float4*>(&Ws[row][c]) = v;
        }
        __syncthreads();
        #pragma unroll
        for (int k2 = 0; k2 < BK; ++k2) {
            float w[TN];
            #pragma unroll
            for (int j = 0; j < TN; ++j) w[j] = Ws[k2][tx * TN + j];
            #pragma unroll
            for (int i = 0; i < 8; ++i) {
                float a = As[ty * 8 + i][k2];
                #pragma unroll
                for (int j = 0; j < TN; ++j) acc[i][j] += a * w[j];
            }
        }
        __syncthreads();
    }
    #pragma unroll
    for (int i = 0; i < 8; ++i) {
        int gr = m0 + ty * 8 + i;
        if (gr >= M) continue;
        #pragma unroll
        for (int j = 0; j < TN; ++j) {
            int gc = cb + tx * TN + j;
            if (gc >= N) continue;
            float v = acc[i][j] + bias[gc];
            if (ACT == 0) v = fmaxf(v, 0.f);
            else v = (v > 0.f) ? v : 0.01f * v;
            C[(size_t)gr * N + gc] = v;
        }
    }
}

extern "C" void kernel_launch(void* const* d_in, const int* in_sizes, int n_in,
                              void* d_out, int out_size, void* d_ws, size_t ws_size,
                              hipStream_t stream) {
    const float* feat = (const float*)d_in[0];
    const int*   src  = (const int*)d_in[1];
    const int*   dst  = (const int*)d_in[2];
    const float* W1   = (const float*)d_in[3];
    const float* b1   = (const float*)d_in[4];
    const float* W2   = (const float*)d_in[5];
    const float* b2   = (const float*)d_in[6];
    const float* Wd1  = (const float*)d_in[7];
    const float* bd1  = (const float*)d_in[8];
    const float* Wd2  = (const float*)d_in[9];
    const float* bd2  = (const float*)d_in[10];
    float* out = (float*)d_out;

    const int N = in_sizes[0] / 128;   // 50000
    const int E = in_sizes[1];         // 800000

    char* ws = (char*)d_ws;
    size_t off = 0;
    auto alloc = [&](size_t bytes) -> void* {
        void* p = ws + off;
        off += (bytes + 255) & ~(size_t)255;
        return p;
    };
    int* deg_out  = (int*)alloc((size_t)N * 4);
    int* deg_in   = (int*)alloc((size_t)N * 4);
    int* fill     = (int*)alloc((size_t)N * 4);
    int* row_ptr  = (int*)alloc((size_t)(N + 1) * 4);
    int* bsum     = (int*)alloc(SCAN_B * 4);
    int* edge_src = (int*)alloc((size_t)E * 4);
    float* inv_out = (float*)alloc((size_t)N * 4);
    float* inv_in  = (float*)alloc((size_t)N * 4);
    float* agg = (float*)alloc((size_t)N * 128 * 4);
    float* h   = (float*)alloc((size_t)N * 128 * 4);
    float* hd  = (float*)alloc((size_t)N * 256 * 4);

    // zero deg_out, deg_in, fill (contiguous span)
    size_t zspan = (char*)fill + (size_t)N * 4 - (char*)deg_out;
    hipMemsetAsync(deg_out, 0, zspan, stream);

    int gE = (E + 255) / 256;
    int gN = (N + SCAN_B - 1) / SCAN_B;
    k_degree<<<gE, 256, 0, stream>>>(src, dst, deg_out, deg_in, E);
    k_invsqrt<<<gN, 256, 0, stream>>>(deg_out, deg_in, inv_out, inv_in, N);
    k_scanA<<<gN, SCAN_B, 0, stream>>>(deg_in, row_ptr, bsum, N);
    k_scanB<<<1, SCAN_B, 0, stream>>>(bsum, gN);
    k_scanC<<<gN, SCAN_B, 0, stream>>>(deg_in, row_ptr, bsum, N, E);
    k_scatter<<<gE, 256, 0, stream>>>(src, dst, row_ptr, fill, edge_src, E);

    int gG = (N + 7) / 8;
    int gM = (N + 63) / 64;

    // layer 1: agg = norm-SpMM(feat); h = relu(agg@W1 + b1)
    k_gather<<<gG, 256, 0, stream>>>(feat, edge_src, row_ptr, inv_out, inv_in, agg, N);
    k_gemm_act<128, 128, 128, 0><<<dim3(gM, 1), 256, 0, stream>>>(agg, W1, b1, h, N);
    // layer 2: agg = norm-SpMM(h); h = relu(agg@W2 + b2)
    k_gather<<<gG, 256, 0, stream>>>(h, edge_src, row_ptr, inv_out, inv_in, agg, N);
    k_gemm_act<128, 128, 128, 0><<<dim3(gM, 1), 256, 0, stream>>>(agg, W2, b2, h, N);
    // DNN: hd = leaky(h@Wd1 + bd1); out = leaky(hd@Wd2 + bd2)
    k_gemm_act<128, 256, 128, 1><<<dim3(gM, 2), 256, 0, stream>>>(h, Wd1, bd1, hd, N);
    k_gemm_act<256, 40, 64, 1><<<dim3(gM, 1), 256, 0, stream>>>(hd, Wd2, bd2, out, N);
}

// Round 2
// 441.658 us; speedup vs baseline: 1.0347x; 1.0347x over previous
//
#include <hip/hip_runtime.h>

// GraphConvModel: 2x GraphConv(norm='both') + 2x Linear+LeakyReLU
// N=50000 nodes, E=800000 edges, feats 128 -> 128 -> 128 -> 256 -> 40 (f32)

#define SCAN_B 256

// ---------------- degree count ----------------
__global__ void k_degree(const int* __restrict__ src, const int* __restrict__ dst,
                         int* __restrict__ deg_out, int* __restrict__ deg_in, int E) {
    int i = blockIdx.x * blockDim.x + threadIdx.x;
    if (i < E) {
        atomicAdd(&deg_out[src[i]], 1);
        atomicAdd(&deg_in[dst[i]], 1);
    }
}

__global__ void k_invsqrt(const int* __restrict__ deg_out, const int* __restrict__ deg_in,
                          float* __restrict__ inv_out, float* __restrict__ inv_in, int N) {
    int i = blockIdx.x * blockDim.x + threadIdx.x;
    if (i < N) {
        inv_out[i] = rsqrtf(fmaxf((float)deg_out[i], 1.0f));
        inv_in[i]  = rsqrtf(fmaxf((float)deg_in[i], 1.0f));
    }
}

// ---------------- exclusive scan of deg_in -> row_ptr (3 kernels) ----------------
__global__ void k_scanA(const int* __restrict__ deg_in, int* __restrict__ incl,
                        int* __restrict__ bsum, int N) {
    __shared__ int s[SCAN_B];
    int t = threadIdx.x, i = blockIdx.x * SCAN_B + t;
    int v = (i < N) ? deg_in[i] : 0;
    s[t] = v; __syncthreads();
    for (int o = 1; o < SCAN_B; o <<= 1) {
        int x = (t >= o) ? s[t - o] : 0;
        __syncthreads();
        s[t] += x;
        __syncthreads();
    }
    if (i < N) incl[i] = s[t];
    if (t == SCAN_B - 1) bsum[blockIdx.x] = s[t];
}

__global__ void k_scanB(int* __restrict__ bsum, int NB) {
    __shared__ int s[SCAN_B];
    int t = threadIdx.x;
    int v = (t < NB) ? bsum[t] : 0;
    s[t] = v; __syncthreads();
    for (int o = 1; o < SCAN_B; o <<= 1) {
        int x = (t >= o) ? s[t - o] : 0;
        __syncthreads();
        s[t] += x;
        __syncthreads();
    }
    if (t < NB) bsum[t] = s[t] - v;  // exclusive
}

__global__ void k_scanC(const int* __restrict__ deg_in, int* __restrict__ row_ptr,
                        const int* __restrict__ bsum, int N, int E) {
    int t = threadIdx.x, i = blockIdx.x * SCAN_B + t;
    if (i < N) row_ptr[i] = row_ptr[i] - deg_in[i] + bsum[blockIdx.x];
    if (i == 0) row_ptr[N] = E;
}

// ---------------- CSR scatter ----------------
__global__ void k_scatter(const int* __restrict__ src, const int* __restrict__ dst,
                          const int* __restrict__ row_ptr, int* __restrict__ fill,
                          int* __restrict__ edge_src, int E) {
    int i = blockIdx.x * blockDim.x + threadIdx.x;
    if (i < E) {
        int d = dst[i];
        int pos = row_ptr[d] + atomicAdd(&fill[d], 1);
        edge_src[pos] = src[i];
    }
}

// ---------------- SpMM gather: Y[i,:] = inv_in[i] * sum_e inv_out[s_e] * X[s_e,:] ----------------
__global__ void k_gather(const float* __restrict__ X, const int* __restrict__ edge_src,
                         const int* __restrict__ row_ptr, const float* __restrict__ inv_out,
                         const float* __restrict__ inv_in, float* __restrict__ Y, int N) {
    int lane = threadIdx.x & 31;
    int row = blockIdx.x * 8 + (threadIdx.x >> 5);
    if (row >= N) return;
    int rs = row_ptr[row], re = row_ptr[row + 1];
    float4 acc = {0.f, 0.f, 0.f, 0.f};
    for (int e = rs; e < re; ++e) {
        int s = edge_src[e];
        float sc = inv_out[s];
        float4 xv = *reinterpret_cast<const float4*>(&X[(size_t)s * 128 + lane * 4]);
        acc.x += xv.x * sc; acc.y += xv.y * sc; acc.z += xv.z * sc; acc.w += xv.w * sc;
    }
    float si = inv_in[row];
    float4 o = {acc.x * si, acc.y * si, acc.z * si, acc.w * si};
    *reinterpret_cast<float4*>(&Y[(size_t)row * 128 + lane * 4]) = o;
}

// ---------------- tiled f32 GEMM + bias + activation (v2) ----------------
// C[M,N] = act(A[M,K] @ W[K,N] + bias), ACT: 0=relu, 1=leaky(0.01)
// 256 threads as 16x16 grid; microtile TM=4 x TN; BM=64, BN=16*TN.
// As stored k-major (transposed) so the A-fragment is one ds_read_b128
// broadcast across 16 lanes; W-fragment is TN/4 ds_read_b128.
template<int K, int N, int BN, int TN, int ACT>
__global__ __launch_bounds__(256) void k_gemm2(const float* __restrict__ A,
                                               const float* __restrict__ W,
                                               const float* __restrict__ bias,
                                               float* __restrict__ C, int M) {
    constexpr int BM = 64, BK = 16;
    constexpr int TM = 4;
    __shared__ float As[BK][BM + 4];   // +4 pad: transpose-write lands 2-way (free)
    __shared__ float Ws[BK][BN];
    int t = threadIdx.x;
    int tx = t & 15, ty = t >> 4;      // 16x16
    int m0 = blockIdx.x * BM;
    int cb = blockIdx.y * BN;

    float acc[TM][TN];
    #pragma unroll
    for (int i = 0; i < TM; ++i)
        #pragma unroll
        for (int j = 0; j < TN; ++j) acc[i][j] = 0.f;

    // A staging addresses: 256 float4 per tile, 1 per thread
    int arow = t >> 2;                 // 0..63
    int akq  = (t & 3) * 4;            // k offset 0,4,8,12
    // W staging: BK x BN = (BN/4)*BK float4; WF4 per row
    constexpr int WF4 = BN / 4;

    for (int kk = 0; kk < K; kk += BK) {
        // stage A (transposed): load float4 along k, write 4 scalars
        {
            float4 v = {0.f, 0.f, 0.f, 0.f};
            int gr = m0 + arow;
            if (gr < M) v = *reinterpret_cast<const float4*>(&A[(size_t)gr * K + kk + akq]);
            As[akq + 0][arow] = v.x;
            As[akq + 1][arow] = v.y;
            As[akq + 2][arow] = v.z;
            As[akq + 3][arow] = v.w;
        }
        // stage W
        #pragma unroll
        for (int i = 0; i < (BK * WF4 + 255) / 256; ++i) {
            int g = t + i * 256;
            if (g < BK * WF4) {
                int r = g / WF4;
                int c = (g % WF4) * 4;
                float4 v = {0.f, 0.f, 0.f, 0.f};
                int gc = cb + c;
                if (gc < N) v = *reinterpret_cast<const float4*>(&W[(size_t)(kk + r) * N + gc]);
                *reinterpret_cast<float4*>(&Ws[r][c]) = v;
            }
        }
        __syncthreads();
        #pragma unroll
        for (int k2 = 0; k2 < BK; ++k2) {
            float4 a = *reinterpret_cast<const float4*>(&As[k2][ty * TM]);
            float w[TN];
            #pragma unroll
            for (int j = 0; j < TN; j += 4) {
                float4 wv = *reinterpret_cast<const float4*>(&Ws[k2][tx * TN + j]);
                w[j] = wv.x; w[j + 1] = wv.y; w[j + 2] = wv.z; w[j + 3] = wv.w;
            }
            float av[TM] = {a.x, a.y, a.z, a.w};
            #pragma unroll
            for (int i = 0; i < TM; ++i)
                #pragma unroll
                for (int j = 0; j < TN; ++j) acc[i][j] += av[i] * w[j];
        }
        __syncthreads();
    }
    #pragma unroll
    for (int i = 0; i < TM; ++i) {
        int gr = m0 + ty * TM + i;
        if (gr >= M) continue;
        #pragma unroll
        for (int j = 0; j < TN; ++j) {
            int gc = cb + tx * TN + j;
            if (gc >= N) continue;
            float v = acc[i][j] + bias[gc];
            if (ACT == 0) v = fmaxf(v, 0.f);
            else v = (v > 0.f) ? v : 0.01f * v;
            C[(size_t)gr * N + gc] = v;
        }
    }
}

extern "C" void kernel_launch(void* const* d_in, const int* in_sizes, int n_in,
                              void* d_out, int out_size, void* d_ws, size_t ws_size,
                              hipStream_t stream) {
    const float* feat = (const float*)d_in[0];
    const int*   src  = (const int*)d_in[1];
    const int*   dst  = (const int*)d_in[2];
    const float* W1   = (const float*)d_in[3];
    const float* b1   = (const float*)d_in[4];
    const float* W2   = (const float*)d_in[5];
    const float* b2   = (const float*)d_in[6];
    const float* Wd1  = (const float*)d_in[7];
    const float* bd1  = (const float*)d_in[8];
    const float* Wd2  = (const float*)d_in[9];
    const float* bd2  = (const float*)d_in[10];
    float* out = (float*)d_out;

    const int N = in_sizes[0] / 128;   // 50000
    const int E = in_sizes[1];         // 800000

    char* ws = (char*)d_ws;
    size_t off = 0;
    auto alloc = [&](size_t bytes) -> void* {
        void* p = ws + off;
        off += (bytes + 255) & ~(size_t)255;
        return p;
    };
    int* deg_out  = (int*)alloc((size_t)N * 4);
    int* deg_in   = (int*)alloc((size_t)N * 4);
    int* fill     = (int*)alloc((size_t)N * 4);
    int* row_ptr  = (int*)alloc((size_t)(N + 1) * 4);
    int* bsum     = (int*)alloc(SCAN_B * 4);
    int* edge_src = (int*)alloc((size_t)E * 4);
    float* inv_out = (float*)alloc((size_t)N * 4);
    float* inv_in  = (float*)alloc((size_t)N * 4);
    float* agg = (float*)alloc((size_t)N * 128 * 4);
    float* h   = (float*)alloc((size_t)N * 128 * 4);
    float* hd  = (float*)alloc((size_t)N * 256 * 4);

    // zero deg_out, deg_in, fill (contiguous span)
    size_t zspan = (char*)fill + (size_t)N * 4 - (char*)deg_out;
    hipMemsetAsync(deg_out, 0, zspan, stream);

    int gE = (E + 255) / 256;
    int gN = (N + SCAN_B - 1) / SCAN_B;
    k_degree<<<gE, 256, 0, stream>>>(src, dst, deg_out, deg_in, E);
    k_invsqrt<<<gN, 256, 0, stream>>>(deg_out, deg_in, inv_out, inv_in, N);
    k_scanA<<<gN, SCAN_B, 0, stream>>>(deg_in, row_ptr, bsum, N);
    k_scanB<<<1, SCAN_B, 0, stream>>>(bsum, gN);
    k_scanC<<<gN, SCAN_B, 0, stream>>>(deg_in, row_ptr, bsum, N, E);
    k_scatter<<<gE, 256, 0, stream>>>(src, dst, row_ptr, fill, edge_src, E);

    int gG = (N + 7) / 8;
    int gM = (N + 63) / 64;

    // layer 1: agg = norm-SpMM(feat); h = relu(agg@W1 + b1)
    k_gather<<<gG, 256, 0, stream>>>(feat, edge_src, row_ptr, inv_out, inv_in, agg, N);
    k_gemm2<128, 128, 128, 8, 0><<<dim3(gM, 1), 256, 0, stream>>>(agg, W1, b1, h, N);
    // layer 2: agg = norm-SpMM(h); h = relu(agg@W2 + b2)
    k_gather<<<gG, 256, 0, stream>>>(h, edge_src, row_ptr, inv_out, inv_in, agg, N);
    k_gemm2<128, 128, 128, 8, 0><<<dim3(gM, 1), 256, 0, stream>>>(agg, W2, b2, h, N);
    // DNN: hd = leaky(h@Wd1 + bd1); out = leaky(hd@Wd2 + bd2)
    k_gemm2<128, 256, 128, 8, 1><<<dim3(gM, 2), 256, 0, stream>>>(h, Wd1, bd1, hd, N);
    k_gemm2<256, 40, 64, 4, 1><<<dim3(gM, 1), 256, 0, stream>>>(hd, Wd2, bd2, out, N);
}

// Round 3
// 391.519 us; speedup vs baseline: 1.1672x; 1.1281x over previous
//
#include <hip/hip_runtime.h>

// GraphConvModel: 2x GraphConv(norm='both') + 2x Linear+LeakyReLU
// N=50000 nodes, E=800000 edges, feats 128 -> 128 -> 128 -> 256 -> 40 (f32)
// GEMMs with K=128 run on MFMA via bf16 hi/lo split (3 MFMA per product).

#define SCAN_B 256

typedef __attribute__((ext_vector_type(8))) short short8v;
typedef __attribute__((ext_vector_type(4))) float f32x4;

// ---------------- degree count ----------------
__global__ void k_degree(const int* __restrict__ src, const int* __restrict__ dst,
                         int* __restrict__ deg_out, int* __restrict__ deg_in, int E) {
    int i = blockIdx.x * blockDim.x + threadIdx.x;
    if (i < E) {
        atomicAdd(&deg_out[src[i]], 1);
        atomicAdd(&deg_in[dst[i]], 1);
    }
}

__global__ void k_invsqrt(const int* __restrict__ deg_out, const int* __restrict__ deg_in,
                          float* __restrict__ inv_out, float* __restrict__ inv_in, int N) {
    int i = blockIdx.x * blockDim.x + threadIdx.x;
    if (i < N) {
        inv_out[i] = rsqrtf(fmaxf((float)deg_out[i], 1.0f));
        inv_in[i]  = rsqrtf(fmaxf((float)deg_in[i], 1.0f));
    }
}

// ---------------- exclusive scan of deg_in -> row_ptr (3 kernels) ----------------
__global__ void k_scanA(const int* __restrict__ deg_in, int* __restrict__ incl,
                        int* __restrict__ bsum, int N) {
    __shared__ int s[SCAN_B];
    int t = threadIdx.x, i = blockIdx.x * SCAN_B + t;
    int v = (i < N) ? deg_in[i] : 0;
    s[t] = v; __syncthreads();
    for (int o = 1; o < SCAN_B; o <<= 1) {
        int x = (t >= o) ? s[t - o] : 0;
        __syncthreads();
        s[t] += x;
        __syncthreads();
    }
    if (i < N) incl[i] = s[t];
    if (t == SCAN_B - 1) bsum[blockIdx.x] = s[t];
}

__global__ void k_scanB(int* __restrict__ bsum, int NB) {
    __shared__ int s[SCAN_B];
    int t = threadIdx.x;
    int v = (t < NB) ? bsum[t] : 0;
    s[t] = v; __syncthreads();
    for (int o = 1; o < SCAN_B; o <<= 1) {
        int x = (t >= o) ? s[t - o] : 0;
        __syncthreads();
        s[t] += x;
        __syncthreads();
    }
    if (t < NB) bsum[t] = s[t] - v;  // exclusive
}

__global__ void k_scanC(const int* __restrict__ deg_in, int* __restrict__ row_ptr,
                        const int* __restrict__ bsum, int N, int E) {
    int t = threadIdx.x, i = blockIdx.x * SCAN_B + t;
    if (i < N) row_ptr[i] = row_ptr[i] - deg_in[i] + bsum[blockIdx.x];
    if (i == 0) row_ptr[N] = E;
}

// ---------------- CSR scatter ----------------
__global__ void k_scatter(const int* __restrict__ src, const int* __restrict__ dst,
                          const int* __restrict__ row_ptr, int* __restrict__ fill,
                          int* __restrict__ edge_src, int E) {
    int i = blockIdx.x * blockDim.x + threadIdx.x;
    if (i < E) {
        int d = dst[i];
        int pos = row_ptr[d] + atomicAdd(&fill[d], 1);
        edge_src[pos] = src[i];
    }
}

// ---------------- SpMM gather ----------------
__global__ void k_gather(const float* __restrict__ X, const int* __restrict__ edge_src,
                         const int* __restrict__ row_ptr, const float* __restrict__ inv_out,
                         const float* __restrict__ inv_in, float* __restrict__ Y, int N) {
    int lane = threadIdx.x & 31;
    int row = blockIdx.x * 8 + (threadIdx.x >> 5);
    if (row >= N) return;
    int rs = row_ptr[row], re = row_ptr[row + 1];
    float4 acc = {0.f, 0.f, 0.f, 0.f};
    for (int e = rs; e < re; ++e) {
        int s = edge_src[e];
        float sc = inv_out[s];
        float4 xv = *reinterpret_cast<const float4*>(&X[(size_t)s * 128 + lane * 4]);
        acc.x += xv.x * sc; acc.y += xv.y * sc; acc.z += xv.z * sc; acc.w += xv.w * sc;
    }
    float si = inv_in[row];
    float4 o = {acc.x * si, acc.y * si, acc.z * si, acc.w * si};
    *reinterpret_cast<float4*>(&Y[(size_t)row * 128 + lane * 4]) = o;
}

// ---------------- bf16 split helpers ----------------
__device__ inline unsigned short bf16_rne(float f) {
    unsigned int u = __float_as_uint(f);
    u += 0x7fffu + ((u >> 16) & 1u);
    return (unsigned short)(u >> 16);
}

__device__ inline void split1(float a, unsigned short& h, unsigned short& l) {
    unsigned short hh = bf16_rne(a);
    float hf = __uint_as_float((unsigned int)hh << 16);
    l = bf16_rne(a - hf);
    h = hh;
}

// ---------------- MFMA GEMM (K=128 fixed): C = act(A[M,128] @ W[128,N] + bias) ----------------
// 256 threads = 4 waves (2x2). BM=128, BN=64, BK=32. W staged once (full K),
// A staged per K-step. All LDS tiles XOR-swizzled: byte ^= (row&7)<<4.
// f32 emulated: a = ah + al (bf16), acc += ah*bh + ah*bl + al*bh.
template<int N, int ACT>
__global__ __launch_bounds__(256) void k_gemm_mfma(const float* __restrict__ A,
                                                   const float* __restrict__ W,
                                                   const float* __restrict__ bias,
                                                   float* __restrict__ C, int M) {
    constexpr int K = 128;
    __shared__ unsigned short Bh[64 * 128], Bl[64 * 128];   // [col][k], 16KB each
    __shared__ unsigned short Ah[128 * 32], Al[128 * 32];   // [row][k], 8KB each

    int t = threadIdx.x;
    int m0 = blockIdx.x * 128;
    int cb = blockIdx.y * 64;

    // ---- stage W for full K (once) ----
    {
        int c = t & 63;
        int kb = (t >> 6) * 32;
        for (int j = 0; j < 32; ++j) {
            int k = kb + j;
            float v = W[(size_t)k * N + cb + c];
            unsigned short hi, lo; split1(v, hi, lo);
            int byte = (c * 256 + 2 * k) ^ ((c & 7) << 4);
            Bh[byte >> 1] = hi;
            Bl[byte >> 1] = lo;
        }
    }

    f32x4 acc[4][2];
    #pragma unroll
    for (int i = 0; i < 4; ++i)
        #pragma unroll
        for (int j = 0; j < 2; ++j)
            acc[i][j] = (f32x4){0.f, 0.f, 0.f, 0.f};

    int lane = t & 63;
    int wave = t >> 6;
    int wm = wave >> 1, wn = wave & 1;
    int lr = lane & 15, lg = lane >> 4;

    for (int kt = 0; kt < K / 32; ++kt) {
        __syncthreads();   // prev-iter reads done (and W stage on iter 0)
        // ---- stage A tile: 128 rows x 32 k ----
        #pragma unroll
        for (int i = 0; i < 4; ++i) {
            int g = i * 256 + t;
            int r = g >> 3;
            int kq = (g & 7) * 4;
            int gr = m0 + r;
            float4 v = {0.f, 0.f, 0.f, 0.f};
            if (gr < M) v = *reinterpret_cast<const float4*>(&A[(size_t)gr * K + kt * 32 + kq]);
            ushort4 h4, l4;
            split1(v.x, h4.x, l4.x);
            split1(v.y, h4.y, l4.y);
            split1(v.z, h4.z, l4.z);
            split1(v.w, h4.w, l4.w);
            int byte = (r * 64 + 2 * kq) ^ ((r & 7) << 4);
            *reinterpret_cast<ushort4*>(&Ah[byte >> 1]) = h4;
            *reinterpret_cast<ushort4*>(&Al[byte >> 1]) = l4;
        }
        __syncthreads();

        // ---- fragments + MFMA ----
        short8v bhf[2], blf[2];
        #pragma unroll
        for (int nf = 0; nf < 2; ++nf) {
            int c = wn * 32 + nf * 16 + lr;
            int byte = (c * 256 + 2 * (kt * 32 + lg * 8)) ^ ((c & 7) << 4);
            bhf[nf] = *reinterpret_cast<const short8v*>(&Bh[byte >> 1]);
            blf[nf] = *reinterpret_cast<const short8v*>(&Bl[byte >> 1]);
        }
        #pragma unroll
        for (int mf = 0; mf < 4; ++mf) {
            int r = wm * 64 + mf * 16 + lr;
            int byte = (r * 64 + 2 * (lg * 8)) ^ ((r & 7) << 4);
            short8v ahf = *reinterpret_cast<const short8v*>(&Ah[byte >> 1]);
            short8v alf = *reinterpret_cast<const short8v*>(&Al[byte >> 1]);
            #pragma unroll
            for (int nf = 0; nf < 2; ++nf) {
                acc[mf][nf] = __builtin_amdgcn_mfma_f32_16x16x32_bf16(ahf, bhf[nf], acc[mf][nf], 0, 0, 0);
                acc[mf][nf] = __builtin_amdgcn_mfma_f32_16x16x32_bf16(ahf, blf[nf], acc[mf][nf], 0, 0, 0);
                acc[mf][nf] = __builtin_amdgcn_mfma_f32_16x16x32_bf16(alf, bhf[nf], acc[mf][nf], 0, 0, 0);
            }
        }
    }

    // ---- epilogue: bias + act, C/D layout col=lane&15, row=(lane>>4)*4+reg ----
    #pragma unroll
    for (int mf = 0; mf < 4; ++mf) {
        #pragma unroll
        for (int nf = 0; nf < 2; ++nf) {
            int col = cb + wn * 32 + nf * 16 + lr;
            float bv = bias[col];
            #pragma unroll
            for (int rg = 0; rg < 4; ++rg) {
                int row = m0 + wm * 64 + mf * 16 + lg * 4 + rg;
                if (row < M) {
                    float v = acc[mf][nf][rg] + bv;
                    if (ACT == 0) v = fmaxf(v, 0.f);
                    else v = (v > 0.f) ? v : 0.01f * v;
                    C[(size_t)row * N + col] = v;
                }
            }
        }
    }
}

// ---------------- VALU GEMM for final layer (K=256, N=40) ----------------
template<int K, int N, int BN, int TN, int ACT>
__global__ __launch_bounds__(256) void k_gemm2(const float* __restrict__ A,
                                               const float* __restrict__ W,
                                               const float* __restrict__ bias,
                                               float* __restrict__ C, int M) {
    constexpr int BM = 64, BK = 16;
    constexpr int TM = 4;
    __shared__ float As[BK][BM + 4];
    __shared__ float Ws[BK][BN];
    int t = threadIdx.x;
    int tx = t & 15, ty = t >> 4;
    int m0 = blockIdx.x * BM;
    int cb = blockIdx.y * BN;

    float acc[TM][TN];
    #pragma unroll
    for (int i = 0; i < TM; ++i)
        #pragma unroll
        for (int j = 0; j < TN; ++j) acc[i][j] = 0.f;

    int arow = t >> 2;
    int akq  = (t & 3) * 4;
    constexpr int WF4 = BN / 4;

    for (int kk = 0; kk < K; kk += BK) {
        {
            float4 v = {0.f, 0.f, 0.f, 0.f};
            int gr = m0 + arow;
            if (gr < M) v = *reinterpret_cast<const float4*>(&A[(size_t)gr * K + kk + akq]);
            As[akq + 0][arow] = v.x;
            As[akq + 1][arow] = v.y;
            As[akq + 2][arow] = v.z;
            As[akq + 3][arow] = v.w;
        }
        #pragma unroll
        for (int i = 0; i < (BK * WF4 + 255) / 256; ++i) {
            int g = t + i * 256;
            if (g < BK * WF4) {
                int r = g / WF4;
                int c = (g % WF4) * 4;
                float4 v = {0.f, 0.f, 0.f, 0.f};
                int gc = cb + c;
                if (gc < N) v = *reinterpret_cast<const float4*>(&W[(size_t)(kk + r) * N + gc]);
                *reinterpret_cast<float4*>(&Ws[r][c]) = v;
            }
        }
        __syncthreads();
        #pragma unroll
        for (int k2 = 0; k2 < BK; ++k2) {
            float4 a = *reinterpret_cast<const float4*>(&As[k2][ty * TM]);
            float w[TN];
            #pragma unroll
            for (int j = 0; j < TN; j += 4) {
                float4 wv = *reinterpret_cast<const float4*>(&Ws[k2][tx * TN + j]);
                w[j] = wv.x; w[j + 1] = wv.y; w[j + 2] = wv.z; w[j + 3] = wv.w;
            }
            float av[TM] = {a.x, a.y, a.z, a.w};
            #pragma unroll
            for (int i = 0; i < TM; ++i)
                #pragma unroll
                for (int j = 0; j < TN; ++j) acc[i][j] += av[i] * w[j];
        }
        __syncthreads();
    }
    #pragma unroll
    for (int i = 0; i < TM; ++i) {
        int gr = m0 + ty * TM + i;
        if (gr >= M) continue;
        #pragma unroll
        for (int j = 0; j < TN; ++j) {
            int gc = cb + tx * TN + j;
            if (gc >= N) continue;
            float v = acc[i][j] + bias[gc];
            if (ACT == 0) v = fmaxf(v, 0.f);
            else v = (v > 0.f) ? v : 0.01f * v;
            C[(size_t)gr * N + gc] = v;
        }
    }
}

extern "C" void kernel_launch(void* const* d_in, const int* in_sizes, int n_in,
                              void* d_out, int out_size, void* d_ws, size_t ws_size,
                              hipStream_t stream) {
    const float* feat = (const float*)d_in[0];
    const int*   src  = (const int*)d_in[1];
    const int*   dst  = (const int*)d_in[2];
    const float* W1   = (const float*)d_in[3];
    const float* b1   = (const float*)d_in[4];
    const float* W2   = (const float*)d_in[5];
    const float* b2   = (const float*)d_in[6];
    const float* Wd1  = (const float*)d_in[7];
    const float* bd1  = (const float*)d_in[8];
    const float* Wd2  = (const float*)d_in[9];
    const float* bd2  = (const float*)d_in[10];
    float* out = (float*)d_out;

    const int N = in_sizes[0] / 128;   // 50000
    const int E = in_sizes[1];         // 800000

    char* ws = (char*)d_ws;
    size_t off = 0;
    auto alloc = [&](size_t bytes) -> void* {
        void* p = ws + off;
        off += (bytes + 255) & ~(size_t)255;
        return p;
    };
    int* deg_out  = (int*)alloc((size_t)N * 4);
    int* deg_in   = (int*)alloc((size_t)N * 4);
    int* fill     = (int*)alloc((size_t)N * 4);
    int* row_ptr  = (int*)alloc((size_t)(N + 1) * 4);
    int* bsum     = (int*)alloc(SCAN_B * 4);
    int* edge_src = (int*)alloc((size_t)E * 4);
    float* inv_out = (float*)alloc((size_t)N * 4);
    float* inv_in  = (float*)alloc((size_t)N * 4);
    float* agg = (float*)alloc((size_t)N * 128 * 4);
    float* h   = (float*)alloc((size_t)N * 128 * 4);
    float* hd  = (float*)alloc((size_t)N * 256 * 4);

    size_t zspan = (char*)fill + (size_t)N * 4 - (char*)deg_out;
    hipMemsetAsync(deg_out, 0, zspan, stream);

    int gE = (E + 255) / 256;
    int gN = (N + SCAN_B - 1) / SCAN_B;
    k_degree<<<gE, 256, 0, stream>>>(src, dst, deg_out, deg_in, E);
    k_invsqrt<<<gN, 256, 0, stream>>>(deg_out, deg_in, inv_out, inv_in, N);
    k_scanA<<<gN, SCAN_B, 0, stream>>>(deg_in, row_ptr, bsum, N);
    k_scanB<<<1, SCAN_B, 0, stream>>>(bsum, gN);
    k_scanC<<<gN, SCAN_B, 0, stream>>>(deg_in, row_ptr, bsum, N, E);
    k_scatter<<<gE, 256, 0, stream>>>(src, dst, row_ptr, fill, edge_src, E);

    int gG = (N + 7) / 8;
    int gMM = (N + 127) / 128;   // MFMA gemm M-tiles
    int gM = (N + 63) / 64;      // VALU gemm M-tiles

    // layer 1
    k_gather<<<gG, 256, 0, stream>>>(feat, edge_src, row_ptr, inv_out, inv_in, agg, N);
    k_gemm_mfma<128, 0><<<dim3(gMM, 2), 256, 0, stream>>>(agg, W1, b1, h, N);
    // layer 2
    k_gather<<<gG, 256, 0, stream>>>(h, edge_src, row_ptr, inv_out, inv_in, agg, N);
    k_gemm_mfma<128, 0><<<dim3(gMM, 2), 256, 0, stream>>>(agg, W2, b2, h, N);
    // DNN
    k_gemm_mfma<256, 1><<<dim3(gMM, 4), 256, 0, stream>>>(h, Wd1, bd1, hd, N);
    k_gemm2<256, 40, 64, 4, 1><<<dim3(gM, 1), 256, 0, stream>>>(hd, Wd2, bd2, out, N);
}

// Round 4
// 379.054 us; speedup vs baseline: 1.2056x; 1.0329x over previous
//
#include <hip/hip_runtime.h>

// GraphConvModel: 2x GraphConv(norm='both') + 2x Linear+LeakyReLU
// N=50000 nodes, E=800000 edges, feats 128 -> 128 -> 128 -> 256 -> 40 (f32)
// All GEMMs on MFMA via bf16 hi/lo split. CSR built with rank-trick
// (count pass's atomic return = in-row position; scatter is atomic-free).

#define SCAN_B 256

typedef __attribute__((ext_vector_type(8))) short short8v;
typedef __attribute__((ext_vector_type(4))) float f32x4;

// ---------------- degree count + rank ----------------
__global__ void k_degree_rank(const int* __restrict__ src, const int* __restrict__ dst,
                              int* __restrict__ deg_out, int* __restrict__ deg_in,
                              int* __restrict__ rank, int E) {
    int i = blockIdx.x * blockDim.x + threadIdx.x;
    if (i < E) {
        atomicAdd(&deg_out[src[i]], 1);
        rank[i] = atomicAdd(&deg_in[dst[i]], 1);
    }
}

// ---------------- exclusive scan of deg_in -> row_ptr (3 kernels) ----------------
__global__ void k_scanA(const int* __restrict__ deg_in, int* __restrict__ incl,
                        int* __restrict__ bsum, int N) {
    __shared__ int s[SCAN_B];
    int t = threadIdx.x, i = blockIdx.x * SCAN_B + t;
    int v = (i < N) ? deg_in[i] : 0;
    s[t] = v; __syncthreads();
    for (int o = 1; o < SCAN_B; o <<= 1) {
        int x = (t >= o) ? s[t - o] : 0;
        __syncthreads();
        s[t] += x;
        __syncthreads();
    }
    if (i < N) incl[i] = s[t];
    if (t == SCAN_B - 1) bsum[blockIdx.x] = s[t];
}

__global__ void k_scanB(int* __restrict__ bsum, int NB) {
    __shared__ int s[SCAN_B];
    int t = threadIdx.x;
    int v = (t < NB) ? bsum[t] : 0;
    s[t] = v; __syncthreads();
    for (int o = 1; o < SCAN_B; o <<= 1) {
        int x = (t >= o) ? s[t - o] : 0;
        __syncthreads();
        s[t] += x;
        __syncthreads();
    }
    if (t < NB) bsum[t] = s[t] - v;  // exclusive
}

__global__ void k_scanC(const int* __restrict__ deg_in, const int* __restrict__ deg_out,
                        int* __restrict__ row_ptr, const int* __restrict__ bsum,
                        float* __restrict__ inv_in, float* __restrict__ inv_out,
                        int N, int E) {
    int t = threadIdx.x, i = blockIdx.x * SCAN_B + t;
    if (i < N) {
        int di = deg_in[i];
        row_ptr[i] = row_ptr[i] - di + bsum[blockIdx.x];
        inv_in[i]  = rsqrtf(fmaxf((float)di, 1.0f));
        inv_out[i] = rsqrtf(fmaxf((float)deg_out[i], 1.0f));
    }
    if (i == 0) row_ptr[N] = E;
}

// ---------------- CSR scatter (no atomics: rank precomputed) ----------------
__global__ void k_scatter2(const int* __restrict__ src, const int* __restrict__ dst,
                           const int* __restrict__ row_ptr, const int* __restrict__ rank,
                           int* __restrict__ edge_src, int E) {
    int i = blockIdx.x * blockDim.x + threadIdx.x;
    if (i < E) {
        edge_src[row_ptr[dst[i]] + rank[i]] = src[i];
    }
}

// ---------------- SpMM gather ----------------
__global__ void k_gather(const float* __restrict__ X, const int* __restrict__ edge_src,
                         const int* __restrict__ row_ptr, const float* __restrict__ inv_out,
                         const float* __restrict__ inv_in, float* __restrict__ Y, int N) {
    int lane = threadIdx.x & 31;
    int row = blockIdx.x * 8 + (threadIdx.x >> 5);
    if (row >= N) return;
    int rs = row_ptr[row], re = row_ptr[row + 1];
    float4 acc = {0.f, 0.f, 0.f, 0.f};
    for (int e = rs; e < re; ++e) {
        int s = edge_src[e];
        float sc = inv_out[s];
        float4 xv = *reinterpret_cast<const float4*>(&X[(size_t)s * 128 + lane * 4]);
        acc.x += xv.x * sc; acc.y += xv.y * sc; acc.z += xv.z * sc; acc.w += xv.w * sc;
    }
    float si = inv_in[row];
    float4 o = {acc.x * si, acc.y * si, acc.z * si, acc.w * si};
    *reinterpret_cast<float4*>(&Y[(size_t)row * 128 + lane * 4]) = o;
}

// ---------------- bf16 split helpers ----------------
__device__ inline unsigned short bf16_rne(float f) {
    unsigned int u = __float_as_uint(f);
    u += 0x7fffu + ((u >> 16) & 1u);
    return (unsigned short)(u >> 16);
}

__device__ inline void split1(float a, unsigned short& h, unsigned short& l) {
    unsigned short hh = bf16_rne(a);
    float hf = __uint_as_float((unsigned int)hh << 16);
    l = bf16_rne(a - hf);
    h = hh;
}

// ---------------- MFMA GEMM: C = act(A[M,K] @ W[K,N] + bias) ----------------
// 256 threads = 4 waves (2x2). BM=128, BN=64(col-tile), full-K W staged once,
// A staged per BK=32. LDS XOR-swizzle: byte ^= (row&7)<<4 (write & read).
// f32 emulated: a = ah + al (bf16), acc += ah*bh + ah*bl + al*bh.
template<int K, int N, int ACT>
__global__ __launch_bounds__(256) void k_gemm_mfma(const float* __restrict__ A,
                                                   const float* __restrict__ W,
                                                   const float* __restrict__ bias,
                                                   float* __restrict__ C, int M) {
    __shared__ unsigned short Bh[64 * K], Bl[64 * K];   // [col][k]
    __shared__ unsigned short Ah[128 * 32], Al[128 * 32];

    int t = threadIdx.x;
    int m0 = blockIdx.x * 128;
    int cb = blockIdx.y * 64;

    // ---- stage W for full K (once) ----
    {
        int c = t & 63;
        int kb = (t >> 6) * (K / 4);
        bool cok = (N % 64 == 0) || (cb + c < N);
        for (int j = 0; j < K / 4; ++j) {
            int k = kb + j;
            float v = cok ? W[(size_t)k * N + cb + c] : 0.f;
            unsigned short hi, lo; split1(v, hi, lo);
            int byte = (c * 2 * K + 2 * k) ^ ((c & 7) << 4);
            Bh[byte >> 1] = hi;
            Bl[byte >> 1] = lo;
        }
    }

    f32x4 acc[4][2];
    #pragma unroll
    for (int i = 0; i < 4; ++i)
        #pragma unroll
        for (int j = 0; j < 2; ++j)
            acc[i][j] = (f32x4){0.f, 0.f, 0.f, 0.f};

    int lane = t & 63;
    int wave = t >> 6;
    int wm = wave >> 1, wn = wave & 1;
    int lr = lane & 15, lg = lane >> 4;

    for (int kt = 0; kt < K / 32; ++kt) {
        __syncthreads();   // prev-iter reads done (and W stage on iter 0)
        // ---- stage A tile: 128 rows x 32 k ----
        #pragma unroll
        for (int i = 0; i < 4; ++i) {
            int g = i * 256 + t;
            int r = g >> 3;
            int kq = (g & 7) * 4;
            int gr = m0 + r;
            float4 v = {0.f, 0.f, 0.f, 0.f};
            if (gr < M) v = *reinterpret_cast<const float4*>(&A[(size_t)gr * K + kt * 32 + kq]);
            ushort4 h4, l4;
            split1(v.x, h4.x, l4.x);
            split1(v.y, h4.y, l4.y);
            split1(v.z, h4.z, l4.z);
            split1(v.w, h4.w, l4.w);
            int byte = (r * 64 + 2 * kq) ^ ((r & 7) << 4);
            *reinterpret_cast<ushort4*>(&Ah[byte >> 1]) = h4;
            *reinterpret_cast<ushort4*>(&Al[byte >> 1]) = l4;
        }
        __syncthreads();

        // ---- fragments + MFMA ----
        short8v bhf[2], blf[2];
        #pragma unroll
        for (int nf = 0; nf < 2; ++nf) {
            int c = wn * 32 + nf * 16 + lr;
            int byte = (c * 2 * K + 2 * (kt * 32 + lg * 8)) ^ ((c & 7) << 4);
            bhf[nf] = *reinterpret_cast<const short8v*>(&Bh[byte >> 1]);
            blf[nf] = *reinterpret_cast<const short8v*>(&Bl[byte >> 1]);
        }
        #pragma unroll
        for (int mf = 0; mf < 4; ++mf) {
            int r = wm * 64 + mf * 16 + lr;
            int byte = (r * 64 + 2 * (lg * 8)) ^ ((r & 7) << 4);
            short8v ahf = *reinterpret_cast<const short8v*>(&Ah[byte >> 1]);
            short8v alf = *reinterpret_cast<const short8v*>(&Al[byte >> 1]);
            #pragma unroll
            for (int nf = 0; nf < 2; ++nf) {
                acc[mf][nf] = __builtin_amdgcn_mfma_f32_16x16x32_bf16(ahf, bhf[nf], acc[mf][nf], 0, 0, 0);
                acc[mf][nf] = __builtin_amdgcn_mfma_f32_16x16x32_bf16(ahf, blf[nf], acc[mf][nf], 0, 0, 0);
                acc[mf][nf] = __builtin_amdgcn_mfma_f32_16x16x32_bf16(alf, bhf[nf], acc[mf][nf], 0, 0, 0);
            }
        }
    }

    // ---- epilogue: bias + act, C/D layout col=lane&15, row=(lane>>4)*4+reg ----
    #pragma unroll
    for (int mf = 0; mf < 4; ++mf) {
        #pragma unroll
        for (int nf = 0; nf < 2; ++nf) {
            int col = cb + wn * 32 + nf * 16 + lr;
            if ((N % 64 != 0) && col >= N) continue;
            float bv = bias[col];
            #pragma unroll
            for (int rg = 0; rg < 4; ++rg) {
                int row = m0 + wm * 64 + mf * 16 + lg * 4 + rg;
                if (row < M) {
                    float v = acc[mf][nf][rg] + bv;
                    if (ACT == 0) v = fmaxf(v, 0.f);
                    else v = (v > 0.f) ? v : 0.01f * v;
                    C[(size_t)row * N + col] = v;
                }
            }
        }
    }
}

extern "C" void kernel_launch(void* const* d_in, const int* in_sizes, int n_in,
                              void* d_out, int out_size, void* d_ws, size_t ws_size,
                              hipStream_t stream) {
    const float* feat = (const float*)d_in[0];
    const int*   src  = (const int*)d_in[1];
    const int*   dst  = (const int*)d_in[2];
    const float* W1   = (const float*)d_in[3];
    const float* b1   = (const float*)d_in[4];
    const float* W2   = (const float*)d_in[5];
    const float* b2   = (const float*)d_in[6];
    const float* Wd1  = (const float*)d_in[7];
    const float* bd1  = (const float*)d_in[8];
    const float* Wd2  = (const float*)d_in[9];
    const float* bd2  = (const float*)d_in[10];
    float* out = (float*)d_out;

    const int N = in_sizes[0] / 128;   // 50000
    const int E = in_sizes[1];         // 800000

    char* ws = (char*)d_ws;
    size_t off = 0;
    auto alloc = [&](size_t bytes) -> void* {
        void* p = ws + off;
        off += (bytes + 255) & ~(size_t)255;
        return p;
    };
    int* deg_out  = (int*)alloc((size_t)N * 4);
    int* deg_in   = (int*)alloc((size_t)N * 4);
    int* row_ptr  = (int*)alloc((size_t)(N + 1) * 4);
    int* bsum     = (int*)alloc(SCAN_B * 4);
    int* rank     = (int*)alloc((size_t)E * 4);
    int* edge_src = (int*)alloc((size_t)E * 4);
    float* inv_out = (float*)alloc((size_t)N * 4);
    float* inv_in  = (float*)alloc((size_t)N * 4);
    float* agg = (float*)alloc((size_t)N * 128 * 4);
    float* h   = (float*)alloc((size_t)N * 128 * 4);
    float* hd  = (float*)alloc((size_t)N * 256 * 4);

    // zero deg_out, deg_in (contiguous span)
    size_t zspan = (char*)deg_in + (size_t)N * 4 - (char*)deg_out;
    hipMemsetAsync(deg_out, 0, zspan, stream);

    int gE = (E + 255) / 256;
    int gN = (N + SCAN_B - 1) / SCAN_B;
    k_degree_rank<<<gE, 256, 0, stream>>>(src, dst, deg_out, deg_in, rank, E);
    k_scanA<<<gN, SCAN_B, 0, stream>>>(deg_in, row_ptr, bsum, N);
    k_scanB<<<1, SCAN_B, 0, stream>>>(bsum, gN);
    k_scanC<<<gN, SCAN_B, 0, stream>>>(deg_in, deg_out, row_ptr, bsum, inv_in, inv_out, N, E);
    k_scatter2<<<gE, 256, 0, stream>>>(src, dst, row_ptr, rank, edge_src, E);

    int gG = (N + 7) / 8;
    int gMM = (N + 127) / 128;   // MFMA gemm M-tiles

    // layer 1
    k_gather<<<gG, 256, 0, stream>>>(feat, edge_src, row_ptr, inv_out, inv_in, agg, N);
    k_gemm_mfma<128, 128, 0><<<dim3(gMM, 2), 256, 0, stream>>>(agg, W1, b1, h, N);
    // layer 2
    k_gather<<<gG, 256, 0, stream>>>(h, edge_src, row_ptr, inv_out, inv_in, agg, N);
    k_gemm_mfma<128, 128, 0><<<dim3(gMM, 2), 256, 0, stream>>>(agg, W2, b2, h, N);
    // DNN
    k_gemm_mfma<128, 256, 1><<<dim3(gMM, 4), 256, 0, stream>>>(h, Wd1, bd1, hd, N);
    k_gemm_mfma<256, 40, 1><<<dim3(gMM, 1), 256, 0, stream>>>(hd, Wd2, bd2, out, N);
}

// Round 5
// 348.505 us; speedup vs baseline: 1.3112x; 1.0877x over previous
//
#include <hip/hip_runtime.h>

// GraphConvModel: 2x GraphConv(norm='both') + 2x Linear+LeakyReLU
// N=50000 nodes, E=800000 edges, feats 128 -> 128 -> 128 -> 256 -> 40 (f32)
// Reorder: G = X@W first (dense, graph-independent), then normalized gather
// with fused bias+relu. Degree atomics fused as prologue of the first GEMM.

#define SCAN_B 256

typedef __attribute__((ext_vector_type(8))) short short8v;
typedef __attribute__((ext_vector_type(4))) float f32x4;

// ---------------- exclusive scan of deg_in -> row_ptr (3 kernels) ----------------
__global__ void k_scanA(const int* __restrict__ deg_in, int* __restrict__ incl,
                        int* __restrict__ bsum, int N) {
    __shared__ int s[SCAN_B];
    int t = threadIdx.x, i = blockIdx.x * SCAN_B + t;
    int v = (i < N) ? deg_in[i] : 0;
    s[t] = v; __syncthreads();
    for (int o = 1; o < SCAN_B; o <<= 1) {
        int x = (t >= o) ? s[t - o] : 0;
        __syncthreads();
        s[t] += x;
        __syncthreads();
    }
    if (i < N) incl[i] = s[t];
    if (t == SCAN_B - 1) bsum[blockIdx.x] = s[t];
}

__global__ void k_scanB(int* __restrict__ bsum, int NB) {
    __shared__ int s[SCAN_B];
    int t = threadIdx.x;
    int v = (t < NB) ? bsum[t] : 0;
    s[t] = v; __syncthreads();
    for (int o = 1; o < SCAN_B; o <<= 1) {
        int x = (t >= o) ? s[t - o] : 0;
        __syncthreads();
        s[t] += x;
        __syncthreads();
    }
    if (t < NB) bsum[t] = s[t] - v;  // exclusive
}

__global__ void k_scanC(const int* __restrict__ deg_in, const int* __restrict__ deg_out,
                        int* __restrict__ row_ptr, const int* __restrict__ bsum,
                        float* __restrict__ inv_in, float* __restrict__ inv_out,
                        int N, int E) {
    int t = threadIdx.x, i = blockIdx.x * SCAN_B + t;
    if (i < N) {
        int di = deg_in[i];
        row_ptr[i] = row_ptr[i] - di + bsum[blockIdx.x];
        inv_in[i]  = rsqrtf(fmaxf((float)di, 1.0f));
        inv_out[i] = rsqrtf(fmaxf((float)deg_out[i], 1.0f));
    }
    if (i == 0) row_ptr[N] = E;
}

// ---------------- CSR scatter (no atomics) + per-edge scale pack ----------------
__global__ void k_scatter3(const int* __restrict__ src, const int* __restrict__ dst,
                           const int* __restrict__ row_ptr, const int* __restrict__ rank,
                           const float* __restrict__ inv_out,
                           int2* __restrict__ edges, int E) {
    int i = blockIdx.x * blockDim.x + threadIdx.x;
    if (i < E) {
        int s = src[i];
        int2 p;
        p.x = s;
        p.y = __float_as_int(inv_out[s]);
        edges[row_ptr[dst[i]] + rank[i]] = p;
    }
}

// ---------------- SpMM gather + bias + relu ----------------
// Y[i,:] = relu(inv_in[i] * sum_e sc_e * X[s_e,:] + bias)
__global__ void k_gather2(const float* __restrict__ X, const int2* __restrict__ edges,
                          const int* __restrict__ row_ptr, const float* __restrict__ inv_in,
                          const float* __restrict__ bias, float* __restrict__ Y, int N) {
    int lane = threadIdx.x & 31;
    int row = blockIdx.x * 8 + (threadIdx.x >> 5);
    if (row >= N) return;
    int rs = row_ptr[row], re = row_ptr[row + 1];
    float4 acc = {0.f, 0.f, 0.f, 0.f};
    int e = rs;
    #define LDROW(s) (*reinterpret_cast<const float4*>(&X[(size_t)(s) * 128 + lane * 4]))
    for (; e + 4 <= re; e += 4) {
        int2 p0 = edges[e], p1 = edges[e + 1], p2 = edges[e + 2], p3 = edges[e + 3];
        float4 x0 = LDROW(p0.x), x1 = LDROW(p1.x), x2 = LDROW(p2.x), x3 = LDROW(p3.x);
        float c0 = __int_as_float(p0.y), c1 = __int_as_float(p1.y);
        float c2 = __int_as_float(p2.y), c3 = __int_as_float(p3.y);
        acc.x += c0 * x0.x + c1 * x1.x + c2 * x2.x + c3 * x3.x;
        acc.y += c0 * x0.y + c1 * x1.y + c2 * x2.y + c3 * x3.y;
        acc.z += c0 * x0.z + c1 * x1.z + c2 * x2.z + c3 * x3.z;
        acc.w += c0 * x0.w + c1 * x1.w + c2 * x2.w + c3 * x3.w;
    }
    for (; e < re; ++e) {
        int2 p = edges[e];
        float c = __int_as_float(p.y);
        float4 xv = LDROW(p.x);
        acc.x += c * xv.x; acc.y += c * xv.y; acc.z += c * xv.z; acc.w += c * xv.w;
    }
    #undef LDROW
    float si = inv_in[row];
    float4 b4 = *reinterpret_cast<const float4*>(&bias[lane * 4]);
    float4 o;
    o.x = fmaxf(fmaf(acc.x, si, b4.x), 0.f);
    o.y = fmaxf(fmaf(acc.y, si, b4.y), 0.f);
    o.z = fmaxf(fmaf(acc.z, si, b4.z), 0.f);
    o.w = fmaxf(fmaf(acc.w, si, b4.w), 0.f);
    *reinterpret_cast<float4*>(&Y[(size_t)row * 128 + lane * 4]) = o;
}

// ---------------- bf16 split helpers ----------------
__device__ inline unsigned short bf16_rne(float f) {
    unsigned int u = __float_as_uint(f);
    u += 0x7fffu + ((u >> 16) & 1u);
    return (unsigned short)(u >> 16);
}

__device__ inline void split1(float a, unsigned short& h, unsigned short& l) {
    unsigned short hh = bf16_rne(a);
    float hf = __uint_as_float((unsigned int)hh << 16);
    l = bf16_rne(a - hf);
    h = hh;
}

// ---------------- MFMA GEMM: C = act(A[M,K] @ W[K,N] + bias) ----------------
// 256 threads = 4 waves (2x2). BM=128, 64-col tile (blockIdx.y), full-K W staged
// once, A staged per BK=32. LDS XOR-swizzle: byte ^= (row&7)<<4.
// f32 emulated: a = ah + al (bf16), acc += ah*bh + ah*bl + al*bh.
// ACT: 0 = bias+relu, 1 = bias+leaky(0.01), 2 = raw (no bias).
// DEG: run a degree/rank atomic prologue over this block's edge slice
// (atomics drain at the memory-side pipe while MFMA work proceeds).
template<int K, int N, int ACT, bool DEG>
__global__ __launch_bounds__(256) void k_gemm_mfma(const float* __restrict__ A,
                                                   const float* __restrict__ W,
                                                   const float* __restrict__ bias,
                                                   float* __restrict__ C, int M,
                                                   const int* __restrict__ src,
                                                   const int* __restrict__ dst,
                                                   int* __restrict__ deg_out,
                                                   int* __restrict__ deg_in,
                                                   int* __restrict__ rank, int E, int epb) {
    __shared__ unsigned short Bh[64 * K], Bl[64 * K];   // [col][k]
    __shared__ unsigned short Ah[128 * 32], Al[128 * 32];

    int t = threadIdx.x;

    if (DEG) {
        int bid = blockIdx.y * gridDim.x + blockIdx.x;
        int base = bid * epb;
        int end = min(E, base + epb);
        for (int i = base + t; i < end; i += 256) {
            atomicAdd(&deg_out[src[i]], 1);
            rank[i] = atomicAdd(&deg_in[dst[i]], 1);
        }
    }

    int m0 = blockIdx.x * 128;
    int cb = blockIdx.y * 64;

    // ---- stage W for full K (once) ----
    {
        int c = t & 63;
        int kb = (t >> 6) * (K / 4);
        bool cok = (N % 64 == 0) || (cb + c < N);
        for (int j = 0; j < K / 4; ++j) {
            int k = kb + j;
            float v = cok ? W[(size_t)k * N + cb + c] : 0.f;
            unsigned short hi, lo; split1(v, hi, lo);
            int byte = (c * 2 * K + 2 * k) ^ ((c & 7) << 4);
            Bh[byte >> 1] = hi;
            Bl[byte >> 1] = lo;
        }
    }

    f32x4 acc[4][2];
    #pragma unroll
    for (int i = 0; i < 4; ++i)
        #pragma unroll
        for (int j = 0; j < 2; ++j)
            acc[i][j] = (f32x4){0.f, 0.f, 0.f, 0.f};

    int lane = t & 63;
    int wave = t >> 6;
    int wm = wave >> 1, wn = wave & 1;
    int lr = lane & 15, lg = lane >> 4;

    for (int kt = 0; kt < K / 32; ++kt) {
        __syncthreads();   // prev-iter reads done (and W stage on iter 0)
        // ---- stage A tile: 128 rows x 32 k ----
        #pragma unroll
        for (int i = 0; i < 4; ++i) {
            int g = i * 256 + t;
            int r = g >> 3;
            int kq = (g & 7) * 4;
            int gr = m0 + r;
            float4 v = {0.f, 0.f, 0.f, 0.f};
            if (gr < M) v = *reinterpret_cast<const float4*>(&A[(size_t)gr * K + kt * 32 + kq]);
            ushort4 h4, l4;
            split1(v.x, h4.x, l4.x);
            split1(v.y, h4.y, l4.y);
            split1(v.z, h4.z, l4.z);
            split1(v.w, h4.w, l4.w);
            int byte = (r * 64 + 2 * kq) ^ ((r & 7) << 4);
            *reinterpret_cast<ushort4*>(&Ah[byte >> 1]) = h4;
            *reinterpret_cast<ushort4*>(&Al[byte >> 1]) = l4;
        }
        __syncthreads();

        // ---- fragments + MFMA ----
        short8v bhf[2], blf[2];
        #pragma unroll
        for (int nf = 0; nf < 2; ++nf) {
            int c = wn * 32 + nf * 16 + lr;
            int byte = (c * 2 * K + 2 * (kt * 32 + lg * 8)) ^ ((c & 7) << 4);
            bhf[nf] = *reinterpret_cast<const short8v*>(&Bh[byte >> 1]);
            blf[nf] = *reinterpret_cast<const short8v*>(&Bl[byte >> 1]);
        }
        #pragma unroll
        for (int mf = 0; mf < 4; ++mf) {
            int r = wm * 64 + mf * 16 + lr;
            int byte = (r * 64 + 2 * (lg * 8)) ^ ((r & 7) << 4);
            short8v ahf = *reinterpret_cast<const short8v*>(&Ah[byte >> 1]);
            short8v alf = *reinterpret_cast<const short8v*>(&Al[byte >> 1]);
            #pragma unroll
            for (int nf = 0; nf < 2; ++nf) {
                acc[mf][nf] = __builtin_amdgcn_mfma_f32_16x16x32_bf16(ahf, bhf[nf], acc[mf][nf], 0, 0, 0);
                acc[mf][nf] = __builtin_amdgcn_mfma_f32_16x16x32_bf16(ahf, blf[nf], acc[mf][nf], 0, 0, 0);
                acc[mf][nf] = __builtin_amdgcn_mfma_f32_16x16x32_bf16(alf, bhf[nf], acc[mf][nf], 0, 0, 0);
            }
        }
    }

    // ---- epilogue: C/D layout col=lane&15, row=(lane>>4)*4+reg ----
    #pragma unroll
    for (int mf = 0; mf < 4; ++mf) {
        #pragma unroll
        for (int nf = 0; nf < 2; ++nf) {
            int col = cb + wn * 32 + nf * 16 + lr;
            if ((N % 64 != 0) && col >= N) continue;
            float bv = (ACT < 2) ? bias[col] : 0.f;
            #pragma unroll
            for (int rg = 0; rg < 4; ++rg) {
                int row = m0 + wm * 64 + mf * 16 + lg * 4 + rg;
                if (row < M) {
                    float v = acc[mf][nf][rg];
                    if (ACT == 0) v = fmaxf(v + bv, 0.f);
                    else if (ACT == 1) { v += bv; v = (v > 0.f) ? v : 0.01f * v; }
                    C[(size_t)row * N + col] = v;
                }
            }
        }
    }
}

extern "C" void kernel_launch(void* const* d_in, const int* in_sizes, int n_in,
                              void* d_out, int out_size, void* d_ws, size_t ws_size,
                              hipStream_t stream) {
    const float* feat = (const float*)d_in[0];
    const int*   src  = (const int*)d_in[1];
    const int*   dst  = (const int*)d_in[2];
    const float* W1   = (const float*)d_in[3];
    const float* b1   = (const float*)d_in[4];
    const float* W2   = (const float*)d_in[5];
    const float* b2   = (const float*)d_in[6];
    const float* Wd1  = (const float*)d_in[7];
    const float* bd1  = (const float*)d_in[8];
    const float* Wd2  = (const float*)d_in[9];
    const float* bd2  = (const float*)d_in[10];
    float* out = (float*)d_out;

    const int N = in_sizes[0] / 128;   // 50000
    const int E = in_sizes[1];         // 800000

    char* ws = (char*)d_ws;
    size_t off = 0;
    auto alloc = [&](size_t bytes) -> void* {
        void* p = ws + off;
        off += (bytes + 255) & ~(size_t)255;
        return p;
    };
    int* deg_out  = (int*)alloc((size_t)N * 4);
    int* deg_in   = (int*)alloc((size_t)N * 4);
    int* row_ptr  = (int*)alloc((size_t)(N + 1) * 4);
    int* bsum     = (int*)alloc(SCAN_B * 4);
    int* rank     = (int*)alloc((size_t)E * 4);
    int2* edges   = (int2*)alloc((size_t)E * 8);
    float* inv_out = (float*)alloc((size_t)N * 4);
    float* inv_in  = (float*)alloc((size_t)N * 4);
    float* bufA = (float*)alloc((size_t)N * 128 * 4);   // G1, then G2
    float* bufB = (float*)alloc((size_t)N * 128 * 4);   // h1, then h2
    float* hd   = (float*)alloc((size_t)N * 256 * 4);

    // zero deg_out, deg_in (contiguous span)
    size_t zspan = (char*)deg_in + (size_t)N * 4 - (char*)deg_out;
    hipMemsetAsync(deg_out, 0, zspan, stream);

    int gE = (E + 255) / 256;
    int gN = (N + SCAN_B - 1) / SCAN_B;
    int gG = (N + 7) / 8;
    int gMM = (N + 127) / 128;         // MFMA M-tiles

    // fused: degree/rank atomics + G1 = feat @ W1 (raw)
    int fusedBlocks = gMM * 2;
    int epb = (E + fusedBlocks - 1) / fusedBlocks;
    k_gemm_mfma<128, 128, 2, true><<<dim3(gMM, 2), 256, 0, stream>>>(
        feat, W1, nullptr, bufA, N, src, dst, deg_out, deg_in, rank, E, epb);

    k_scanA<<<gN, SCAN_B, 0, stream>>>(deg_in, row_ptr, bsum, N);
    k_scanB<<<1, SCAN_B, 0, stream>>>(bsum, gN);
    k_scanC<<<gN, SCAN_B, 0, stream>>>(deg_in, deg_out, row_ptr, bsum, inv_in, inv_out, N, E);
    k_scatter3<<<gE, 256, 0, stream>>>(src, dst, row_ptr, rank, inv_out, edges, E);

    // layer 1 gather: h1 = relu(norm-agg(G1) + b1)
    k_gather2<<<gG, 256, 0, stream>>>(bufA, edges, row_ptr, inv_in, b1, bufB, N);
    // layer 2: G2 = h1 @ W2 ; h2 = relu(norm-agg(G2) + b2)
    k_gemm_mfma<128, 128, 2, false><<<dim3(gMM, 2), 256, 0, stream>>>(
        bufB, W2, nullptr, bufA, N, nullptr, nullptr, nullptr, nullptr, nullptr, 0, 0);
    k_gather2<<<gG, 256, 0, stream>>>(bufA, edges, row_ptr, inv_in, b2, bufB, N);
    // DNN
    k_gemm_mfma<128, 256, 1, false><<<dim3(gMM, 4), 256, 0, stream>>>(
        bufB, Wd1, bd1, hd, N, nullptr, nullptr, nullptr, nullptr, nullptr, 0, 0);
    k_gemm_mfma<256, 40, 1, false><<<dim3(gMM, 1), 256, 0, stream>>>(
        hd, Wd2, bd2, out, N, nullptr, nullptr, nullptr, nullptr, nullptr, 0, 0);
}

// Round 6
// 337.108 us; speedup vs baseline: 1.3556x; 1.0338x over previous
//
#include <hip/hip_runtime.h>

// GraphConvModel: 2x GraphConv(norm='both') + 2x Linear+LeakyReLU
// N=50000 nodes, E=800000 edges, feats 128 -> 128 -> 128 -> 256 -> 40 (f32)
// Reorder: G = X@W first (dense, graph-independent), then normalized gather
// with fused bias+relu. Degree atomics run in SPECIALIZED BLOCKS of the first
// GEMM launch (block-level concurrency; in-wave fusion failed in R4).

#define SCAN_B 256

typedef __attribute__((ext_vector_type(8))) short short8v;
typedef __attribute__((ext_vector_type(4))) float f32x4;

// ---------------- exclusive scan of deg_in -> row_ptr (3 kernels) ----------------
__global__ void k_scanA(const int* __restrict__ deg_in, int* __restrict__ incl,
                        int* __restrict__ bsum, int N) {
    __shared__ int s[SCAN_B];
    int t = threadIdx.x, i = blockIdx.x * SCAN_B + t;
    int v = (i < N) ? deg_in[i] : 0;
    s[t] = v; __syncthreads();
    for (int o = 1; o < SCAN_B; o <<= 1) {
        int x = (t >= o) ? s[t - o] : 0;
        __syncthreads();
        s[t] += x;
        __syncthreads();
    }
    if (i < N) incl[i] = s[t];
    if (t == SCAN_B - 1) bsum[blockIdx.x] = s[t];
}

__global__ void k_scanB(int* __restrict__ bsum, int NB) {
    __shared__ int s[SCAN_B];
    int t = threadIdx.x;
    int v = (t < NB) ? bsum[t] : 0;
    s[t] = v; __syncthreads();
    for (int o = 1; o < SCAN_B; o <<= 1) {
        int x = (t >= o) ? s[t - o] : 0;
        __syncthreads();
        s[t] += x;
        __syncthreads();
    }
    if (t < NB) bsum[t] = s[t] - v;  // exclusive
}

__global__ void k_scanC(const int* __restrict__ deg_in, const int* __restrict__ deg_out,
                        int* __restrict__ row_ptr, const int* __restrict__ bsum,
                        float* __restrict__ inv_in, float* __restrict__ inv_out,
                        int N, int E) {
    int t = threadIdx.x, i = blockIdx.x * SCAN_B + t;
    if (i < N) {
        int di = deg_in[i];
        row_ptr[i] = row_ptr[i] - di + bsum[blockIdx.x];
        inv_in[i]  = rsqrtf(fmaxf((float)di, 1.0f));
        inv_out[i] = rsqrtf(fmaxf((float)deg_out[i], 1.0f));
    }
    if (i == 0) row_ptr[N] = E;
}

// ---------------- CSR scatter (no atomics) + per-edge scale pack ----------------
__global__ void k_scatter3(const int* __restrict__ src, const int* __restrict__ dst,
                           const int* __restrict__ row_ptr, const int* __restrict__ rank,
                           const float* __restrict__ inv_out,
                           int2* __restrict__ edges, int E) {
    int i = blockIdx.x * blockDim.x + threadIdx.x;
    if (i < E) {
        int s = src[i];
        int2 p;
        p.x = s;
        p.y = __float_as_int(inv_out[s]);
        edges[row_ptr[dst[i]] + rank[i]] = p;
    }
}

// ---------------- SpMM gather + bias + relu ----------------
// Y[i,:] = relu(inv_in[i] * sum_e sc_e * X[s_e,:] + bias)
__global__ void k_gather2(const float* __restrict__ X, const int2* __restrict__ edges,
                          const int* __restrict__ row_ptr, const float* __restrict__ inv_in,
                          const float* __restrict__ bias, float* __restrict__ Y, int N) {
    int lane = threadIdx.x & 31;
    int row = blockIdx.x * 8 + (threadIdx.x >> 5);
    if (row >= N) return;
    int rs = row_ptr[row], re = row_ptr[row + 1];
    float4 acc = {0.f, 0.f, 0.f, 0.f};
    int e = rs;
    #define LDROW(s) (*reinterpret_cast<const float4*>(&X[(size_t)(s) * 128 + lane * 4]))
    for (; e + 4 <= re; e += 4) {
        int2 p0 = edges[e], p1 = edges[e + 1], p2 = edges[e + 2], p3 = edges[e + 3];
        float4 x0 = LDROW(p0.x), x1 = LDROW(p1.x), x2 = LDROW(p2.x), x3 = LDROW(p3.x);
        float c0 = __int_as_float(p0.y), c1 = __int_as_float(p1.y);
        float c2 = __int_as_float(p2.y), c3 = __int_as_float(p3.y);
        acc.x += c0 * x0.x + c1 * x1.x + c2 * x2.x + c3 * x3.x;
        acc.y += c0 * x0.y + c1 * x1.y + c2 * x2.y + c3 * x3.y;
        acc.z += c0 * x0.z + c1 * x1.z + c2 * x2.z + c3 * x3.z;
        acc.w += c0 * x0.w + c1 * x1.w + c2 * x2.w + c3 * x3.w;
    }
    for (; e < re; ++e) {
        int2 p = edges[e];
        float c = __int_as_float(p.y);
        float4 xv = LDROW(p.x);
        acc.x += c * xv.x; acc.y += c * xv.y; acc.z += c * xv.z; acc.w += c * xv.w;
    }
    #undef LDROW
    float si = inv_in[row];
    float4 b4 = *reinterpret_cast<const float4*>(&bias[lane * 4]);
    float4 o;
    o.x = fmaxf(fmaf(acc.x, si, b4.x), 0.f);
    o.y = fmaxf(fmaf(acc.y, si, b4.y), 0.f);
    o.z = fmaxf(fmaf(acc.z, si, b4.z), 0.f);
    o.w = fmaxf(fmaf(acc.w, si, b4.w), 0.f);
    *reinterpret_cast<float4*>(&Y[(size_t)row * 128 + lane * 4]) = o;
}

// ---------------- bf16 split helpers ----------------
__device__ inline unsigned short bf16_rne(float f) {
    unsigned int u = __float_as_uint(f);
    u += 0x7fffu + ((u >> 16) & 1u);
    return (unsigned short)(u >> 16);
}

__device__ inline void split1(float a, unsigned short& h, unsigned short& l) {
    unsigned short hh = bf16_rne(a);
    float hf = __uint_as_float((unsigned int)hh << 16);
    l = bf16_rne(a - hf);
    h = hh;
}

// ---------------- MFMA GEMM: C = act(A[M,K] @ W[K,N] + bias) ----------------
// 256 threads = 4 waves (2x2). BM=128, 64-col tiles, full-K W staged once,
// A staged per BK=32. LDS XOR-swizzle: byte ^= (row&7)<<4.
// f32 emulated: a = ah + al (bf16), acc += ah*bh + ah*bl + al*bh.
// ACT: 0 = bias+relu, 1 = bias+leaky(0.01), 2 = raw (no bias).
// DEG: blocks [0, degb) run ONLY the degree/rank atomic histogram and exit;
// blocks [degb, ...) are GEMM tiles (1D grid, tile = bid - degb).
template<int K, int N, int ACT, bool DEG>
__global__ __launch_bounds__(256) void k_gemm_mfma(const float* __restrict__ A,
                                                   const float* __restrict__ W,
                                                   const float* __restrict__ bias,
                                                   float* __restrict__ C, int M,
                                                   const int* __restrict__ src,
                                                   const int* __restrict__ dst,
                                                   int* __restrict__ deg_out,
                                                   int* __restrict__ deg_in,
                                                   int* __restrict__ rank, int E, int epb,
                                                   int gmm, int degb) {
    __shared__ unsigned short Bh[64 * K], Bl[64 * K];   // [col][k]
    __shared__ unsigned short Ah[128 * 32], Al[128 * 32];

    int t = threadIdx.x;
    int m0, cb;
    if (DEG) {
        int bid = blockIdx.x;
        if (bid < degb) {
            int base = bid * epb;
            int end = min(E, base + epb);
            for (int i = base + t; i < end; i += 256) {
                atomicAdd(&deg_out[src[i]], 1);
                rank[i] = atomicAdd(&deg_in[dst[i]], 1);
            }
            return;
        }
        int tile = bid - degb;
        m0 = (tile % gmm) * 128;
        cb = (tile / gmm) * 64;
    } else {
        m0 = blockIdx.x * 128;
        cb = blockIdx.y * 64;
    }

    // ---- stage W for full K (once) ----
    {
        int c = t & 63;
        int kb = (t >> 6) * (K / 4);
        bool cok = (N % 64 == 0) || (cb + c < N);
        for (int j = 0; j < K / 4; ++j) {
            int k = kb + j;
            float v = cok ? W[(size_t)k * N + cb + c] : 0.f;
            unsigned short hi, lo; split1(v, hi, lo);
            int byte = (c * 2 * K + 2 * k) ^ ((c & 7) << 4);
            Bh[byte >> 1] = hi;
            Bl[byte >> 1] = lo;
        }
    }

    f32x4 acc[4][2];
    #pragma unroll
    for (int i = 0; i < 4; ++i)
        #pragma unroll
        for (int j = 0; j < 2; ++j)
            acc[i][j] = (f32x4){0.f, 0.f, 0.f, 0.f};

    int lane = t & 63;
    int wave = t >> 6;
    int wm = wave >> 1, wn = wave & 1;
    int lr = lane & 15, lg = lane >> 4;

    for (int kt = 0; kt < K / 32; ++kt) {
        __syncthreads();   // prev-iter reads done (and W stage on iter 0)
        // ---- stage A tile: 128 rows x 32 k ----
        #pragma unroll
        for (int i = 0; i < 4; ++i) {
            int g = i * 256 + t;
            int r = g >> 3;
            int kq = (g & 7) * 4;
            int gr = m0 + r;
            float4 v = {0.f, 0.f, 0.f, 0.f};
            if (gr < M) v = *reinterpret_cast<const float4*>(&A[(size_t)gr * K + kt * 32 + kq]);
            ushort4 h4, l4;
            split1(v.x, h4.x, l4.x);
            split1(v.y, h4.y, l4.y);
            split1(v.z, h4.z, l4.z);
            split1(v.w, h4.w, l4.w);
            int byte = (r * 64 + 2 * kq) ^ ((r & 7) << 4);
            *reinterpret_cast<ushort4*>(&Ah[byte >> 1]) = h4;
            *reinterpret_cast<ushort4*>(&Al[byte >> 1]) = l4;
        }
        __syncthreads();

        // ---- fragments + MFMA ----
        short8v bhf[2], blf[2];
        #pragma unroll
        for (int nf = 0; nf < 2; ++nf) {
            int c = wn * 32 + nf * 16 + lr;
            int byte = (c * 2 * K + 2 * (kt * 32 + lg * 8)) ^ ((c & 7) << 4);
            bhf[nf] = *reinterpret_cast<const short8v*>(&Bh[byte >> 1]);
            blf[nf] = *reinterpret_cast<const short8v*>(&Bl[byte >> 1]);
        }
        #pragma unroll
        for (int mf = 0; mf < 4; ++mf) {
            int r = wm * 64 + mf * 16 + lr;
            int byte = (r * 64 + 2 * (lg * 8)) ^ ((r & 7) << 4);
            short8v ahf = *reinterpret_cast<const short8v*>(&Ah[byte >> 1]);
            short8v alf = *reinterpret_cast<const short8v*>(&Al[byte >> 1]);
            #pragma unroll
            for (int nf = 0; nf < 2; ++nf) {
                acc[mf][nf] = __builtin_amdgcn_mfma_f32_16x16x32_bf16(ahf, bhf[nf], acc[mf][nf], 0, 0, 0);
                acc[mf][nf] = __builtin_amdgcn_mfma_f32_16x16x32_bf16(ahf, blf[nf], acc[mf][nf], 0, 0, 0);
                acc[mf][nf] = __builtin_amdgcn_mfma_f32_16x16x32_bf16(alf, bhf[nf], acc[mf][nf], 0, 0, 0);
            }
        }
    }

    // ---- epilogue: C/D layout col=lane&15, row=(lane>>4)*4+reg ----
    #pragma unroll
    for (int mf = 0; mf < 4; ++mf) {
        #pragma unroll
        for (int nf = 0; nf < 2; ++nf) {
            int col = cb + wn * 32 + nf * 16 + lr;
            if ((N % 64 != 0) && col >= N) continue;
            float bv = (ACT < 2) ? bias[col] : 0.f;
            #pragma unroll
            for (int rg = 0; rg < 4; ++rg) {
                int row = m0 + wm * 64 + mf * 16 + lg * 4 + rg;
                if (row < M) {
                    float v = acc[mf][nf][rg];
                    if (ACT == 0) v = fmaxf(v + bv, 0.f);
                    else if (ACT == 1) { v += bv; v = (v > 0.f) ? v : 0.01f * v; }
                    C[(size_t)row * N + col] = v;
                }
            }
        }
    }
}

extern "C" void kernel_launch(void* const* d_in, const int* in_sizes, int n_in,
                              void* d_out, int out_size, void* d_ws, size_t ws_size,
                              hipStream_t stream) {
    const float* feat = (const float*)d_in[0];
    const int*   src  = (const int*)d_in[1];
    const int*   dst  = (const int*)d_in[2];
    const float* W1   = (const float*)d_in[3];
    const float* b1   = (const float*)d_in[4];
    const float* W2   = (const float*)d_in[5];
    const float* b2   = (const float*)d_in[6];
    const float* Wd1  = (const float*)d_in[7];
    const float* bd1  = (const float*)d_in[8];
    const float* Wd2  = (const float*)d_in[9];
    const float* bd2  = (const float*)d_in[10];
    float* out = (float*)d_out;

    const int N = in_sizes[0] / 128;   // 50000
    const int E = in_sizes[1];         // 800000

    char* ws = (char*)d_ws;
    size_t off = 0;
    auto alloc = [&](size_t bytes) -> void* {
        void* p = ws + off;
        off += (bytes + 255) & ~(size_t)255;
        return p;
    };
    int* deg_out  = (int*)alloc((size_t)N * 4);
    int* deg_in   = (int*)alloc((size_t)N * 4);
    int* row_ptr  = (int*)alloc((size_t)(N + 1) * 4);
    int* bsum     = (int*)alloc(SCAN_B * 4);
    int* rank     = (int*)alloc((size_t)E * 4);
    int2* edges   = (int2*)alloc((size_t)E * 8);
    float* inv_out = (float*)alloc((size_t)N * 4);
    float* inv_in  = (float*)alloc((size_t)N * 4);
    float* bufA = (float*)alloc((size_t)N * 128 * 4);   // G1, then G2
    float* bufB = (float*)alloc((size_t)N * 128 * 4);   // h1, then h2
    float* hd   = (float*)alloc((size_t)N * 256 * 4);

    // zero deg_out, deg_in (contiguous span)
    size_t zspan = (char*)deg_in + (size_t)N * 4 - (char*)deg_out;
    hipMemsetAsync(deg_out, 0, zspan, stream);

    int gE = (E + 255) / 256;
    int gN = (N + SCAN_B - 1) / SCAN_B;
    int gG = (N + 7) / 8;
    int gMM = (N + 127) / 128;         // MFMA M-tiles

    // fused launch: blocks [0,DEGB) = degree/rank atomics; rest = G1 = feat@W1 tiles.
    // Block-level specialization -> atomic drain and MFMA run on different CUs.
    const int DEGB = 512;
    int epb = (E + DEGB - 1) / DEGB;
    k_gemm_mfma<128, 128, 2, true><<<DEGB + gMM * 2, 256, 0, stream>>>(
        feat, W1, nullptr, bufA, N, src, dst, deg_out, deg_in, rank, E, epb, gMM, DEGB);

    k_scanA<<<gN, SCAN_B, 0, stream>>>(deg_in, row_ptr, bsum, N);
    k_scanB<<<1, SCAN_B, 0, stream>>>(bsum, gN);
    k_scanC<<<gN, SCAN_B, 0, stream>>>(deg_in, deg_out, row_ptr, bsum, inv_in, inv_out, N, E);
    k_scatter3<<<gE, 256, 0, stream>>>(src, dst, row_ptr, rank, inv_out, edges, E);

    // layer 1 gather: h1 = relu(norm-agg(G1) + b1)
    k_gather2<<<gG, 256, 0, stream>>>(bufA, edges, row_ptr, inv_in, b1, bufB, N);
    // layer 2: G2 = h1 @ W2 ; h2 = relu(norm-agg(G2) + b2)
    k_gemm_mfma<128, 128, 2, false><<<dim3(gMM, 2), 256, 0, stream>>>(
        bufB, W2, nullptr, bufA, N, nullptr, nullptr, nullptr, nullptr, nullptr, 0, 0, 0, 0);
    k_gather2<<<gG, 256, 0, stream>>>(bufA, edges, row_ptr, inv_in, b2, bufB, N);
    // DNN
    k_gemm_mfma<128, 256, 1, false><<<dim3(gMM, 4), 256, 0, stream>>>(
        bufB, Wd1, bd1, hd, N, nullptr, nullptr, nullptr, nullptr, nullptr, 0, 0, 0, 0);
    k_gemm_mfma<256, 40, 1, false><<<dim3(gMM, 1), 256, 0, stream>>>(
        hd, Wd2, bd2, out, N, nullptr, nullptr, nullptr, nullptr, nullptr, 0, 0, 0, 0);
}